// Round 13
// baseline (53.601 us; speedup 1.0000x reference)
//
#include <hip/hip_runtime.h>

typedef unsigned short ushort_t;
typedef unsigned int uint_t;
typedef short short8 __attribute__((ext_vector_type(8)));
typedef float f32x4 __attribute__((ext_vector_type(4)));

namespace {

template<int CTRL, int RM>
__device__ __forceinline__ float dpp_mov0(float v) {
  return __int_as_float(__builtin_amdgcn_update_dpp(
      0, __float_as_int(v), CTRL, RM, 0xF, false));
}
template<int CTRL, int RM>
__device__ __forceinline__ float dpp_mov1(float v) {
  return __int_as_float(__builtin_amdgcn_update_dpp(
      0x3f800000, __float_as_int(v), CTRL, RM, 0xF, false));
}

__device__ __forceinline__ float rl(float v, int k) {
  return __int_as_float(__builtin_amdgcn_readlane(__float_as_int(v), k));
}

// A_bar apply via joint 2-var linear-recurrence DPP scan (HW-verified r1-r12,
// absmax <= 4.9e-4). Coefs hoisted (data-independent).
struct Hoist {
  float cs0, cs1, cs2, cs3, cs4, cs5;
  float gs0, gs1, gs2, gs3, gs4, gs5;
  float r, inv_d, hr, alpha, k2;
};

__device__ __forceinline__ Hoist make_hoist(float dt, int n) {
  float h = 0.5f * dt, fn = (float)n;
  float r = sqrtf(2.f * fn + 1.f);
  float d = 1.f + h * (fn + 1.f);
  float inv_d = 1.f / d;
  float g = (1.f - h * fn) * inv_d;
  float c = g - 1.f;
  Hoist H;
  H.r = r; H.inv_d = inv_d; H.hr = h * r;
  H.alpha = 1.f + h * fn;
  H.k2 = r * (2.f - d) * inv_d;
#define COEF_STEP(IDX, CTRL, RM)                                        \
  H.cs##IDX = c; H.gs##IDX = g;                                         \
  { float cP = dpp_mov0<CTRL, RM>(c);                                   \
    float gP = dpp_mov1<CTRL, RM>(g);                                   \
    c = fmaf(g, cP, c); g = g * gP; }
  COEF_STEP(0, 0x111, 0xF)
  COEF_STEP(1, 0x112, 0xF)
  COEF_STEP(2, 0x114, 0xF)
  COEF_STEP(3, 0x118, 0xF)
  COEF_STEP(4, 0x142, 0xA)
  COEF_STEP(5, 0x143, 0xC)
#undef COEF_STEP
  return H;
}

__device__ __forceinline__ float abar_apply(float x, const Hoist& H) {
  float w1 = H.r * x, w2 = H.k2 * x;
#define APPLY_STEP(IDX, CTRL, RM)                                       \
  { float w1P = dpp_mov0<CTRL, RM>(w1);                                 \
    float w2P = dpp_mov0<CTRL, RM>(w2);                                 \
    w2 = fmaf(H.cs##IDX, w1P, fmaf(H.gs##IDX, w2P, w2));                \
    w1 += w1P; }
  APPLY_STEP(0, 0x111, 0xF)
  APPLY_STEP(1, 0x112, 0xF)
  APPLY_STEP(2, 0x114, 0xF)
  APPLY_STEP(3, 0x118, 0xF)
  APPLY_STEP(4, 0x142, 0xA)
  APPLY_STEP(5, 0x143, 0xC)
#undef APPLY_STEP
  float tp = dpp_mov0<0x138, 0xF>(w2);           // wave_shr:1
  return H.inv_d * fmaf(-H.hr, w1 + tp, H.alpha * x);
}

template<int CTRL, int RM>
__device__ __forceinline__ void linrec_step(float& G, float& W) {
  float Wo = dpp_mov0<CTRL, RM>(W);
  float Go = dpp_mov1<CTRL, RM>(G);
  W = fmaf(G, Wo, W);
  G *= Go;
}
__device__ __forceinline__ float lhs_solve(float z, const Hoist& H) {
  float G = H.gs0, W = H.r * z * H.inv_d;
  linrec_step<0x111, 0xF>(G, W);
  linrec_step<0x112, 0xF>(G, W);
  linrec_step<0x114, 0xF>(G, W);
  linrec_step<0x118, 0xF>(G, W);
  linrec_step<0x142, 0xA>(G, W);
  linrec_step<0x143, 0xC>(G, W);
  float sp = dpp_mov0<0x138, 0xF>(W);
  return (z - H.hr * sp) * H.inv_d;
}

__device__ __forceinline__ float softplus_dt(float ldt) {
  return log1pf(expf(ldt)) + 1e-6f;
}

// Pin a 64-float row in registers (R12; prevents remat/demotion).
#define KEEP4(v) asm volatile("" : "+v"(v.x), "+v"(v.y), "+v"(v.z), "+v"(v.w))

__device__ __forceinline__ void load_row_pin(const float* __restrict__ base,
                                             float4 (&p)[16]) {
  const float4* p4 = (const float4*)base;
  #pragma unroll
  for (int q = 0; q < 16; ++q) p[q] = p4[q];
  #pragma unroll
  for (int q = 0; q < 16; ++q) KEEP4(p[q]);
}

__device__ __forceinline__ float qapply_pin(const float4 (&p)[16], float u) {
  float a0 = 0.f, a1 = 0.f, a2 = 0.f, a3 = 0.f;
  #pragma unroll
  for (int q = 0; q < 16; ++q) {
    a0 = fmaf(p[q].x, rl(u, 4 * q + 0), a0);
    a1 = fmaf(p[q].y, rl(u, 4 * q + 1), a1);
    a2 = fmaf(p[q].z, rl(u, 4 * q + 2), a2);
    a3 = fmaf(p[q].w, rl(u, 4 * q + 3), a3);
  }
  return (a0 + a1) + (a2 + a3);
}

// streaming matvec from global row (one float4 live at a time) — seeds only
__device__ __forceinline__ float grow_matvec(const float* __restrict__ M,
                                             float u, int lane) {
  float a0 = 0.f, a1 = 0.f, a2 = 0.f, a3 = 0.f;
  const float4* m4 = (const float4*)(M + lane * 64);
  #pragma unroll
  for (int q = 0; q < 16; ++q) {
    float4 f = m4[q];
    a0 = fmaf(f.x, rl(u, 4 * q + 0), a0);
    a1 = fmaf(f.y, rl(u, 4 * q + 1), a1);
    a2 = fmaf(f.z, rl(u, 4 * q + 2), a2);
    a3 = fmaf(f.w, rl(u, 4 * q + 3), a3);
  }
  return (a0 + a1) + (a2 + a3);
}

// bf16 error-compensated split store into chunk-XOR-swizzled LDS (R7-verified)
__device__ __forceinline__ void split_store(float v, ushort_t* Hi,
                                            ushort_t* Lo, int row, int n) {
  uint_t uv = __float_as_uint(v);
  float hf = __uint_as_float(uv & 0xFFFF0000u);
  uint_t lv = __float_as_uint(v - hf);
  int idx = (row << 6) | (((n >> 3) ^ (row & 7)) << 3) | (n & 7);
  Hi[idx] = (ushort_t)(uv >> 16);
  Lo[idx] = (ushort_t)(lv >> 16);
}

__device__ __forceinline__ int frag_off(int row, int chunk) {
  return (row << 6) | ((chunk ^ (row & 7)) << 3);
}

// device-scope flag sync among the 64 PREP blocks only (trivially co-resident;
// mechanism HW-validated in R11 where prep's Q2-via-matvec passed refcheck).
__device__ __forceinline__ void wait_cnt(const uint_t* f, uint_t tgt) {
  while (__hip_atomic_load(f, __ATOMIC_ACQUIRE, __HIP_MEMORY_SCOPE_AGENT) < tgt)
    __builtin_amdgcn_s_sleep(8);
}
__device__ __forceinline__ void signal_cnt(uint_t* f, int lane) {
  __threadfence();
  if (lane == 0)
    __hip_atomic_fetch_add(f, 1u, __ATOMIC_RELEASE, __HIP_MEMORY_SCOPE_AGENT);
}

} // namespace

// Prep: 64 blocks, 64 serial applies (HALF of R7's 128), snapshotting
// A16/A32/A48 (scatter row-major) + A64 (QROW coalesced + A64RM scatter).
// Q2 = A64*A64 and Q4 = Q2*Q2 via flag-synced cross-block matvecs.
__global__ __launch_bounds__(64) void hippo_prep(
    const float* __restrict__ ldt_p, uint_t* __restrict__ flags,
    float* __restrict__ A16c, float* __restrict__ A32c,
    float* __restrict__ A48c, float* __restrict__ QROW,
    float* __restrict__ A64RM, float* __restrict__ Q2ROW,
    float* __restrict__ Q2RM, float* __restrict__ Q4ROW) {
  const int lane = threadIdx.x;
  const int m = blockIdx.x;
  const float dt = softplus_dt(ldt_p[0]);
  const Hoist H = make_hoist(dt, lane);
  float x = (lane == m) ? 1.f : 0.f;
  #pragma unroll 1
  for (int s = 0; s < 16; ++s) x = abar_apply(x, H);
  A16c[lane * 64 + m] = x;               // A16[n][k] row-major (scatter)
  #pragma unroll 1
  for (int s = 0; s < 16; ++s) x = abar_apply(x, H);
  A32c[lane * 64 + m] = x;
  #pragma unroll 1
  for (int s = 0; s < 16; ++s) x = abar_apply(x, H);
  A48c[lane * 64 + m] = x;
  #pragma unroll 1
  for (int s = 0; s < 16; ++s) x = abar_apply(x, H);
  QROW[m * 64 + lane] = x;               // Q row m = A64 col m (coalesced)
  A64RM[lane * 64 + m] = x;              // A64 row-major (scatter)
  signal_cnt(&flags[0], lane);
  wait_cnt(&flags[0], 64);               // all of A64 visible
  {
    float4 p[16];
    load_row_pin(A64RM + lane * 64, p);  // p[k] = A64[lane][k]
    float x2 = qapply_pin(p, x);         // A128[lane][m]
    Q2ROW[m * 64 + lane] = x2;           // Q2 row m (coalesced)
    Q2RM[lane * 64 + m] = x2;            // A128 row-major (scatter)
    signal_cnt(&flags[1], lane);
    wait_cnt(&flags[1], 64);
    float4 p2[16];
    load_row_pin(Q2RM + lane * 64, p2);  // p2[k] = A128[lane][k]
    float x4 = qapply_pin(p2, x2);       // A256[lane][m]
    Q4ROW[m * 64 + lane] = x4;           // Q4 row m (coalesced)
  }
}

// Main: R7 skeleton with every serial chain halved + 2-way chain ILP.
//  w0: V rows 0-15 & 16-31 interleaved (seeds Bb, A16*Bb)
//  w3: V rows 32-47 & 48-63 interleaved (seeds A32*Bb, A48*Bb)
//  w1: U rows {0,2}+4a interleaved Q4-chains (seeds C, Q2*C)
//  w2: U rows {1,3}+4a interleaved Q4-chains (seeds Q*C, Q2*Q*C)
//  Epilogue: 12 mfma_f32_16x16x32_bf16 per wave (bf16x2 split, R7-verified).
__global__ __launch_bounds__(256) void hippo_main(
    const float* __restrict__ B, const float* __restrict__ C,
    const float* __restrict__ Dv, const float* __restrict__ ldt_p,
    const float* __restrict__ A16c, const float* __restrict__ A32c,
    const float* __restrict__ A48c, const float* __restrict__ QROW,
    const float* __restrict__ Q2ROW, const float* __restrict__ Q4ROW,
    float* __restrict__ out) {
  __shared__ __align__(16) ushort_t Uh[32 * 64], Ulo[32 * 64];
  __shared__ __align__(16) ushort_t Vh[64 * 64], Vlo[64 * 64];
  const int d = blockIdx.x;
  const int tau = threadIdx.x;
  const int lane = tau & 63;
  const int w = tau >> 6;
  const float dt = softplus_dt(ldt_p[0]);

  if ((w & 1) == 0) {  // V waves: w0 -> rows 0..31, w2...
  }
  if (w == 0 || w == 3) {
    const Hoist H = make_hoist(dt, lane);
    float bb = lhs_solve(dt * B[d * 64 + lane], H);
    float va, vb;
    int j0;
    if (w == 0) {
      va = bb;                                  // V0
      vb = grow_matvec(A16c, bb, lane);         // V16 = A16 * Bbar
      j0 = 0;
    } else {
      va = grow_matvec(A32c, bb, lane);         // V32
      vb = grow_matvec(A48c, bb, lane);         // V48
      j0 = 32;
    }
    #pragma unroll 1
    for (int jj = 0; jj < 16; ++jj) {
      split_store(va, Vh, Vlo, j0 + jj, lane);
      split_store(vb, Vh, Vlo, j0 + 16 + jj, lane);
      if (jj < 15) {                            // two independent DPP chains
        va = abar_apply(va, H);
        vb = abar_apply(vb, H);
      }
    }
  } else {
    float ua, ub;
    int i0;
    if (w == 1) {
      ua = C[d * 64 + lane];                    // u0
      ub = grow_matvec(Q2ROW, ua, lane);        // u2 = Q2 u0
      i0 = 0;
    } else {
      ua = grow_matvec(QROW, C[d * 64 + lane], lane);   // u1 = Q u0
      ub = grow_matvec(Q2ROW, ua, lane);        // u3 = Q2 u1
      i0 = 1;
    }
    float4 p[16];
    load_row_pin(Q4ROW + lane * 64, p);         // p = Q4[lane][:], pinned
    #pragma unroll 1
    for (int a = 0; a < 8; ++a) {
      split_store(ua, Uh, Ulo, (a << 2) + i0, lane);
      split_store(ub, Uh, Ulo, (a << 2) + i0 + 2, lane);
      if (a < 7) {                              // two independent chains
        ua = qapply_pin(p, ua);
        ub = qapply_pin(p, ub);
      }
    }
  }
  __syncthreads();

  // MFMA epilogue (R7-verified): D(32x64) = U(32x64) . V(64x64)^T, bf16x2.
  const int it = w & 1;
  const int jp = w >> 1;
  const int arow = lane & 15;
  const int kg = lane >> 4;
  f32x4 acc0 = {0.f, 0.f, 0.f, 0.f};
  f32x4 acc1 = {0.f, 0.f, 0.f, 0.f};
  const int ia = (it << 4) + arow;
  const int jv0 = (jp << 5) + arow;
  const int jv1 = jv0 + 16;
  #pragma unroll
  for (int k0 = 0; k0 < 2; ++k0) {
    const int ci = (k0 << 2) + kg;
    short8 ah = *(const short8*)&Uh[frag_off(ia, ci)];
    short8 al = *(const short8*)&Ulo[frag_off(ia, ci)];
    short8 b0h = *(const short8*)&Vh[frag_off(jv0, ci)];
    short8 b0l = *(const short8*)&Vlo[frag_off(jv0, ci)];
    short8 b1h = *(const short8*)&Vh[frag_off(jv1, ci)];
    short8 b1l = *(const short8*)&Vlo[frag_off(jv1, ci)];
    acc0 = __builtin_amdgcn_mfma_f32_16x16x32_bf16(ah, b0h, acc0, 0, 0, 0);
    acc0 = __builtin_amdgcn_mfma_f32_16x16x32_bf16(al, b0h, acc0, 0, 0, 0);
    acc0 = __builtin_amdgcn_mfma_f32_16x16x32_bf16(ah, b0l, acc0, 0, 0, 0);
    acc1 = __builtin_amdgcn_mfma_f32_16x16x32_bf16(ah, b1h, acc1, 0, 0, 0);
    acc1 = __builtin_amdgcn_mfma_f32_16x16x32_bf16(al, b1h, acc1, 0, 0, 0);
    acc1 = __builtin_amdgcn_mfma_f32_16x16x32_bf16(ah, b1l, acc1, 0, 0, 0);
  }
  // C/D layout (m89-verified): col = lane&15, row = (lane>>4)*4 + reg.
  #pragma unroll
  for (int r = 0; r < 4; ++r) {
    const int i = (it << 4) + (kg << 2) + r;
    const int j0 = (jp << 5) + arow;
    float y0 = acc0[r];
    if (i == 0 && j0 == 0) y0 += Dv[d];
    out[((size_t)d << 11) + (i << 6) + j0] = y0;
    out[((size_t)d << 11) + (i << 6) + j0 + 16] = acc1[r];
  }
}

extern "C" void kernel_launch(void* const* d_in, const int* in_sizes, int n_in,
                              void* d_out, int out_size, void* d_ws, size_t ws_size,
                              hipStream_t stream) {
  const float* B   = (const float*)d_in[0];
  const float* C   = (const float*)d_in[1];
  const float* Dv  = (const float*)d_in[2];
  const float* ldt = (const float*)d_in[3];
  const int d_model = in_sizes[2];        // 1024

  char* ws = (char*)d_ws;
  uint_t* flags = (uint_t*)ws;                         // 256 B
  float* A16c  = (float*)(ws + 256);                   // 16 KiB each
  float* A32c  = (float*)(ws + 256 + 16384 * 1);
  float* A48c  = (float*)(ws + 256 + 16384 * 2);
  float* QROW  = (float*)(ws + 256 + 16384 * 3);
  float* A64RM = (float*)(ws + 256 + 16384 * 4);
  float* Q2ROW = (float*)(ws + 256 + 16384 * 5);
  float* Q2RM  = (float*)(ws + 256 + 16384 * 6);
  float* Q4ROW = (float*)(ws + 256 + 16384 * 7);

  hipMemsetAsync(flags, 0, 256, stream);   // graph-capturable memset node
  hippo_prep<<<64, 64, 0, stream>>>(ldt, flags, A16c, A32c, A48c, QROW,
                                    A64RM, Q2ROW, Q2RM, Q4ROW);
  hippo_main<<<d_model, 256, 0, stream>>>(B, C, Dv, ldt, A16c, A32c, A48c,
                                          QROW, Q2ROW, Q4ROW, (float*)d_out);
}

// Round 15
// 41.344 us; speedup vs baseline: 1.2964x; 1.2964x over previous
//
#include <hip/hip_runtime.h>

typedef unsigned short ushort_t;
typedef unsigned int uint_t;
typedef short short8 __attribute__((ext_vector_type(8)));
typedef float f32x4 __attribute__((ext_vector_type(4)));

namespace {

template<int CTRL, int RM>
__device__ __forceinline__ float dpp_mov0(float v) {
  return __int_as_float(__builtin_amdgcn_update_dpp(
      0, __float_as_int(v), CTRL, RM, 0xF, false));
}
template<int CTRL, int RM>
__device__ __forceinline__ float dpp_mov1(float v) {
  return __int_as_float(__builtin_amdgcn_update_dpp(
      0x3f800000, __float_as_int(v), CTRL, RM, 0xF, false));
}

__device__ __forceinline__ float rl(float v, int k) {
  return __int_as_float(__builtin_amdgcn_readlane(__float_as_int(v), k));
}

// A_bar apply via joint 2-var linear-recurrence DPP scan (HW-verified r1-r13,
// absmax <= 4.9e-4). Coefs hoisted (data-independent).
struct Hoist {
  float cs0, cs1, cs2, cs3, cs4, cs5;
  float gs0, gs1, gs2, gs3, gs4, gs5;
  float r, inv_d, hr, alpha, k2;
};

__device__ __forceinline__ Hoist make_hoist(float dt, int n) {
  float h = 0.5f * dt, fn = (float)n;
  float r = sqrtf(2.f * fn + 1.f);
  float d = 1.f + h * (fn + 1.f);
  float inv_d = 1.f / d;
  float g = (1.f - h * fn) * inv_d;
  float c = g - 1.f;
  Hoist H;
  H.r = r; H.inv_d = inv_d; H.hr = h * r;
  H.alpha = 1.f + h * fn;
  H.k2 = r * (2.f - d) * inv_d;
#define COEF_STEP(IDX, CTRL, RM)                                        \
  H.cs##IDX = c; H.gs##IDX = g;                                         \
  { float cP = dpp_mov0<CTRL, RM>(c);                                   \
    float gP = dpp_mov1<CTRL, RM>(g);                                   \
    c = fmaf(g, cP, c); g = g * gP; }
  COEF_STEP(0, 0x111, 0xF)
  COEF_STEP(1, 0x112, 0xF)
  COEF_STEP(2, 0x114, 0xF)
  COEF_STEP(3, 0x118, 0xF)
  COEF_STEP(4, 0x142, 0xA)
  COEF_STEP(5, 0x143, 0xC)
#undef COEF_STEP
  return H;
}

__device__ __forceinline__ float abar_apply(float x, const Hoist& H) {
  float w1 = H.r * x, w2 = H.k2 * x;
#define APPLY_STEP(IDX, CTRL, RM)                                       \
  { float w1P = dpp_mov0<CTRL, RM>(w1);                                 \
    float w2P = dpp_mov0<CTRL, RM>(w2);                                 \
    w2 = fmaf(H.cs##IDX, w1P, fmaf(H.gs##IDX, w2P, w2));                \
    w1 += w1P; }
  APPLY_STEP(0, 0x111, 0xF)
  APPLY_STEP(1, 0x112, 0xF)
  APPLY_STEP(2, 0x114, 0xF)
  APPLY_STEP(3, 0x118, 0xF)
  APPLY_STEP(4, 0x142, 0xA)
  APPLY_STEP(5, 0x143, 0xC)
#undef APPLY_STEP
  float tp = dpp_mov0<0x138, 0xF>(w2);           // wave_shr:1
  return H.inv_d * fmaf(-H.hr, w1 + tp, H.alpha * x);
}

template<int CTRL, int RM>
__device__ __forceinline__ void linrec_step(float& G, float& W) {
  float Wo = dpp_mov0<CTRL, RM>(W);
  float Go = dpp_mov1<CTRL, RM>(G);
  W = fmaf(G, Wo, W);
  G *= Go;
}
__device__ __forceinline__ float lhs_solve(float z, const Hoist& H) {
  float G = H.gs0, W = H.r * z * H.inv_d;
  linrec_step<0x111, 0xF>(G, W);
  linrec_step<0x112, 0xF>(G, W);
  linrec_step<0x114, 0xF>(G, W);
  linrec_step<0x118, 0xF>(G, W);
  linrec_step<0x142, 0xA>(G, W);
  linrec_step<0x143, 0xC>(G, W);
  float sp = dpp_mov0<0x138, 0xF>(W);
  return (z - H.hr * sp) * H.inv_d;
}

__device__ __forceinline__ float softplus_dt(float ldt) {
  return log1pf(expf(ldt)) + 1e-6f;
}

// Pin a 64-float row in registers (R12; prevents remat/demotion).
#define KEEP4(v) asm volatile("" : "+v"(v.x), "+v"(v.y), "+v"(v.z), "+v"(v.w))

__device__ __forceinline__ void load_row_pin(const float* __restrict__ base,
                                             float4 (&p)[16]) {
  const float4* p4 = (const float4*)base;
  #pragma unroll
  for (int q = 0; q < 16; ++q) p[q] = p4[q];
  #pragma unroll
  for (int q = 0; q < 16; ++q) KEEP4(p[q]);
}

__device__ __forceinline__ float qapply_pin(const float4 (&p)[16], float u) {
  float a0 = 0.f, a1 = 0.f, a2 = 0.f, a3 = 0.f;
  #pragma unroll
  for (int q = 0; q < 16; ++q) {
    a0 = fmaf(p[q].x, rl(u, 4 * q + 0), a0);
    a1 = fmaf(p[q].y, rl(u, 4 * q + 1), a1);
    a2 = fmaf(p[q].z, rl(u, 4 * q + 2), a2);
    a3 = fmaf(p[q].w, rl(u, 4 * q + 3), a3);
  }
  return (a0 + a1) + (a2 + a3);
}

// streaming matvec from global row (one float4 live at a time) — seeds only
__device__ __forceinline__ float grow_matvec(const float* __restrict__ M,
                                             float u, int lane) {
  float a0 = 0.f, a1 = 0.f, a2 = 0.f, a3 = 0.f;
  const float4* m4 = (const float4*)(M + lane * 64);
  #pragma unroll
  for (int q = 0; q < 16; ++q) {
    float4 f = m4[q];
    a0 = fmaf(f.x, rl(u, 4 * q + 0), a0);
    a1 = fmaf(f.y, rl(u, 4 * q + 1), a1);
    a2 = fmaf(f.z, rl(u, 4 * q + 2), a2);
    a3 = fmaf(f.w, rl(u, 4 * q + 3), a3);
  }
  return (a0 + a1) + (a2 + a3);
}

// bf16 error-compensated split store into chunk-XOR-swizzled LDS (R7-verified)
__device__ __forceinline__ void split_store(float v, ushort_t* Hi,
                                            ushort_t* Lo, int row, int n) {
  uint_t uv = __float_as_uint(v);
  float hf = __uint_as_float(uv & 0xFFFF0000u);
  uint_t lv = __float_as_uint(v - hf);
  int idx = (row << 6) | (((n >> 3) ^ (row & 7)) << 3) | (n & 7);
  Hi[idx] = (ushort_t)(uv >> 16);
  Lo[idx] = (ushort_t)(lv >> 16);
}

__device__ __forceinline__ int frag_off(int row, int chunk) {
  return (row << 6) | ((chunk ^ (row & 7)) << 3);
}

} // namespace

// Prep: block m chains e_m through 128 applies (self-contained, no sync).
//   s=16/32/48: A^s row-major snapshots (scatter) — V ILP-2 seeds
//   s=64 : col m of A64  = Q-row m   -> QROW  (coalesced)
//   s=128: col m of A128 = Q^2-row m -> Q2ROW (coalesced)
__global__ __launch_bounds__(64) void hippo_pow(const float* __restrict__ ldt_p,
                                                float* __restrict__ A16c,
                                                float* __restrict__ A32c,
                                                float* __restrict__ A48c,
                                                float* __restrict__ QROW,
                                                float* __restrict__ Q2ROW) {
  const int lane = threadIdx.x;
  const int m = blockIdx.x;
  const float dt = softplus_dt(ldt_p[0]);
  const Hoist H = make_hoist(dt, lane);
  float x = (lane == m) ? 1.f : 0.f;
  #pragma unroll 1
  for (int s = 0; s < 16; ++s) x = abar_apply(x, H);
  A16c[lane * 64 + m] = x;
  #pragma unroll 1
  for (int s = 0; s < 16; ++s) x = abar_apply(x, H);
  A32c[lane * 64 + m] = x;
  #pragma unroll 1
  for (int s = 0; s < 16; ++s) x = abar_apply(x, H);
  A48c[lane * 64 + m] = x;
  #pragma unroll 1
  for (int s = 0; s < 16; ++s) x = abar_apply(x, H);
  QROW[m * 64 + lane] = x;
  #pragma unroll 1
  for (int s = 0; s < 64; ++s) x = abar_apply(x, H);
  Q2ROW[m * 64 + lane] = x;
}

// Main (R12 base + R13's refcheck-passed V ILP-2):
//  w0: V rows 0-15 & 16-31 (two interleaved depth-15 chains; seeds Bb, A16*Bb)
//  w3: V rows 32-47 & 48-63 (seeds A32*Bb, A48*Bb)
//  w1: U even (pinned Q^2 chain);  w2: U odd (Q seed + pinned Q^2 chain)
//  Epilogue: 12 mfma_f32_16x16x32_bf16 per wave (bf16x2 split, R7-verified).
__global__ __launch_bounds__(256) void hippo_main(
    const float* __restrict__ B, const float* __restrict__ C,
    const float* __restrict__ Dv, const float* __restrict__ ldt_p,
    const float* __restrict__ A16c, const float* __restrict__ A32c,
    const float* __restrict__ A48c, const float* __restrict__ QROW,
    const float* __restrict__ Q2ROW, float* __restrict__ out) {
  __shared__ __align__(16) ushort_t Uh[32 * 64], Ulo[32 * 64];
  __shared__ __align__(16) ushort_t Vh[64 * 64], Vlo[64 * 64];
  const int d = blockIdx.x;
  const int tau = threadIdx.x;
  const int lane = tau & 63;
  const int w = tau >> 6;
  const float dt = softplus_dt(ldt_p[0]);

  if (w == 0 || w == 3) {
    const Hoist H = make_hoist(dt, lane);
    float bb = lhs_solve(dt * B[d * 64 + lane], H);
    float va, vb;
    int j0;
    if (w == 0) {
      va = bb;                                  // V0
      vb = grow_matvec(A16c, bb, lane);         // V16 = A16 * Bbar
      j0 = 0;
    } else {
      va = grow_matvec(A32c, bb, lane);         // V32
      vb = grow_matvec(A48c, bb, lane);         // V48
      j0 = 32;
    }
    #pragma unroll 1
    for (int jj = 0; jj < 16; ++jj) {
      split_store(va, Vh, Vlo, j0 + jj, lane);
      split_store(vb, Vh, Vlo, j0 + 16 + jj, lane);
      if (jj < 15) {                            // two independent DPP chains
        va = abar_apply(va, H);
        vb = abar_apply(vb, H);
      }
    }
  } else if (w == 1) {
    float4 p[16];
    load_row_pin(Q2ROW + lane * 64, p);         // p = Q2[lane][:], PINNED
    float u = C[d * 64 + lane];
    #pragma unroll 1
    for (int a = 0; a < 16; ++a) {
      split_store(u, Uh, Ulo, 2 * a, lane);
      if (a < 15) u = qapply_pin(p, u);
    }
  } else {  // w == 2
    float u = grow_matvec(QROW, C[d * 64 + lane], lane);   // u1 = Q u0
    float4 p[16];
    load_row_pin(Q2ROW + lane * 64, p);
    #pragma unroll 1
    for (int a = 0; a < 16; ++a) {
      split_store(u, Uh, Ulo, 2 * a + 1, lane);
      if (a < 15) u = qapply_pin(p, u);
    }
  }
  __syncthreads();

  // MFMA epilogue (R7-verified): D(32x64) = U(32x64) . V(64x64)^T, bf16x2.
  const int it = w & 1;
  const int jp = w >> 1;
  const int arow = lane & 15;
  const int kg = lane >> 4;
  f32x4 acc0 = {0.f, 0.f, 0.f, 0.f};
  f32x4 acc1 = {0.f, 0.f, 0.f, 0.f};
  const int ia = (it << 4) + arow;
  const int jv0 = (jp << 5) + arow;
  const int jv1 = jv0 + 16;
  #pragma unroll
  for (int k0 = 0; k0 < 2; ++k0) {
    const int ci = (k0 << 2) + kg;
    short8 ah = *(const short8*)&Uh[frag_off(ia, ci)];
    short8 al = *(const short8*)&Ulo[frag_off(ia, ci)];
    short8 b0h = *(const short8*)&Vh[frag_off(jv0, ci)];
    short8 b0l = *(const short8*)&Vlo[frag_off(jv0, ci)];
    short8 b1h = *(const short8*)&Vh[frag_off(jv1, ci)];
    short8 b1l = *(const short8*)&Vlo[frag_off(jv1, ci)];
    acc0 = __builtin_amdgcn_mfma_f32_16x16x32_bf16(ah, b0h, acc0, 0, 0, 0);
    acc0 = __builtin_amdgcn_mfma_f32_16x16x32_bf16(al, b0h, acc0, 0, 0, 0);
    acc0 = __builtin_amdgcn_mfma_f32_16x16x32_bf16(ah, b0l, acc0, 0, 0, 0);
    acc1 = __builtin_amdgcn_mfma_f32_16x16x32_bf16(ah, b1h, acc1, 0, 0, 0);
    acc1 = __builtin_amdgcn_mfma_f32_16x16x32_bf16(al, b1h, acc1, 0, 0, 0);
    acc1 = __builtin_amdgcn_mfma_f32_16x16x32_bf16(ah, b1l, acc1, 0, 0, 0);
  }
  // C/D layout (m89-verified): col = lane&15, row = (lane>>4)*4 + reg.
  #pragma unroll
  for (int r = 0; r < 4; ++r) {
    const int i = (it << 4) + (kg << 2) + r;
    const int j0 = (jp << 5) + arow;
    float y0 = acc0[r];
    if (i == 0 && j0 == 0) y0 += Dv[d];
    out[((size_t)d << 11) + (i << 6) + j0] = y0;
    out[((size_t)d << 11) + (i << 6) + j0 + 16] = acc1[r];
  }
}

extern "C" void kernel_launch(void* const* d_in, const int* in_sizes, int n_in,
                              void* d_out, int out_size, void* d_ws, size_t ws_size,
                              hipStream_t stream) {
  const float* B   = (const float*)d_in[0];
  const float* C   = (const float*)d_in[1];
  const float* Dv  = (const float*)d_in[2];
  const float* ldt = (const float*)d_in[3];
  const int d_model = in_sizes[2];        // 1024

  char* ws = (char*)d_ws;
  float* A16c  = (float*)(ws);                   // 16 KiB each
  float* A32c  = (float*)(ws + 16384 * 1);
  float* A48c  = (float*)(ws + 16384 * 2);
  float* QROW  = (float*)(ws + 16384 * 3);
  float* Q2ROW = (float*)(ws + 16384 * 4);

  hippo_pow<<<64, 64, 0, stream>>>(ldt, A16c, A32c, A48c, QROW, Q2ROW);
  hippo_main<<<d_model, 256, 0, stream>>>(B, C, Dv, ldt, A16c, A32c, A48c,
                                          QROW, Q2ROW, (float*)d_out);
}